// Round 1
// baseline (1357.985 us; speedup 1.0000x reference)
//
#include <hip/hip_runtime.h>
#include <hip/hip_bf16.h>

typedef unsigned short u16;
typedef unsigned int   u32;
typedef __attribute__((ext_vector_type(8))) short short8;
typedef __attribute__((ext_vector_type(4))) float f32x4;
typedef __attribute__((ext_vector_type(4))) unsigned short u16x4;

#define E_    2048
#define H_    16
#define DH_   128
#define B_    2
#define T_    2048
#define NTOK  4096      // B*T
#define QKVN  6144      // 3*E

__device__ __forceinline__ u16 f2bf(float f) {
  union { float f; u32 u; } v; v.f = f;
  u32 r = (v.u + 0x7FFFu + ((v.u >> 16) & 1u)) >> 16;
  return (u16)r;
}

// ---------------------------------------------------------------- prep kernels

// wqkv_t[n][e] (bf16, n = sec*2048 + h*128 + d) from wq/wk/wv[h][e][d]; bias concat
__global__ __launch_bounds__(256) void prep_qkv(
    const float* __restrict__ wq, const float* __restrict__ wk, const float* __restrict__ wv,
    const float* __restrict__ bq, const float* __restrict__ bk, const float* __restrict__ bv,
    u16* __restrict__ wt, float* __restrict__ bias)
{
  size_t idx = (size_t)blockIdx.x * 256 + threadIdx.x;   // over 6144*2048
  int n = (int)(idx >> 11);
  int e = (int)(idx & 2047);
  int sec = n >> 11;
  int hd  = n & 2047;
  const float* w = (sec == 0) ? wq : (sec == 1) ? wk : wv;
  float v = w[(size_t)(hd >> 7) * (E_ * DH_) + (size_t)e * DH_ + (hd & 127)];
  wt[idx] = f2bf(v);
  if (idx < QKVN) {
    int s2 = (int)(idx >> 11);
    const float* bb = (s2 == 0) ? bq : (s2 == 1) ? bk : bv;
    bias[idx] = bb[idx & 2047];
  }
}

// out[n][k] = bf16(in[k][n]); K = 1<<kshift
__global__ __launch_bounds__(256) void prep_t(
    const float* __restrict__ in, u16* __restrict__ out, int kshift, int N)
{
  size_t idx = (size_t)blockIdx.x * 256 + threadIdx.x;
  size_t n = idx >> kshift;
  size_t k = idx & ((1u << kshift) - 1u);
  out[idx] = f2bf(in[k * (size_t)N + n]);
}

// ---------------------------------------------------------------- rmsnorm (fp32 in, bf16 out)
__global__ __launch_bounds__(256) void rmsnorm_k(
    const float* __restrict__ x, const float* __restrict__ g, u16* __restrict__ o)
{
  const int row = blockIdx.x;
  const float4* xr = (const float4*)(x + (size_t)row * E_);
  const float4* gr = (const float4*)g;
  const int tid = threadIdx.x;
  float4 a0 = xr[tid], a1 = xr[tid + 256];
  float s = a0.x*a0.x + a0.y*a0.y + a0.z*a0.z + a0.w*a0.w
          + a1.x*a1.x + a1.y*a1.y + a1.z*a1.z + a1.w*a1.w;
  #pragma unroll
  for (int m = 1; m < 64; m <<= 1) s += __shfl_xor(s, m);
  __shared__ float wsum[4];
  if ((tid & 63) == 0) wsum[tid >> 6] = s;
  __syncthreads();
  float tot = wsum[0] + wsum[1] + wsum[2] + wsum[3];
  float rinv = rsqrtf(tot * (1.0f / E_) + 1e-8f);
  float4 g0 = gr[tid], g1 = gr[tid + 256];
  u16x4 o0, o1;
  o0[0] = f2bf(a0.x * g0.x * rinv); o0[1] = f2bf(a0.y * g0.y * rinv);
  o0[2] = f2bf(a0.z * g0.z * rinv); o0[3] = f2bf(a0.w * g0.w * rinv);
  o1[0] = f2bf(a1.x * g1.x * rinv); o1[1] = f2bf(a1.y * g1.y * rinv);
  o1[2] = f2bf(a1.z * g1.z * rinv); o1[3] = f2bf(a1.w * g1.w * rinv);
  u16x4* orow = (u16x4*)(o + (size_t)row * E_);
  orow[tid] = o0;
  orow[tid + 256] = o1;
}

// ---------------------------------------------------------------- GEMM (m97 structure)
__device__ __forceinline__ void gload_lds16(const void* g, u16* lds_base) {
  __builtin_amdgcn_global_load_lds(
      (const __attribute__((address_space(1))) u32*)g,
      (__attribute__((address_space(3))) u32*)lds_base, 16, 0, 0);
}

// EPI: 0 = bf16 out (+bias), 1 = f32 out (+bias+resid), 2 = bf16 out (+bias, exact GELU)
template<int EPI>
__global__ __launch_bounds__(256)
void gemm_bt(const u16* __restrict__ A, const u16* __restrict__ Bt,
             const float* __restrict__ bias, const float* __restrict__ resid,
             void* __restrict__ out, int M, int N, int K)
{
  __shared__ __align__(16) u16 As[128 * 32];
  __shared__ __align__(16) u16 Bs[128 * 32];
  const int tid  = threadIdx.x;
  const int lane = tid & 63;
  const int l15  = lane & 15, lg = lane >> 4;
  const int w    = tid >> 6;
  const int wm   = (w & 1) * 64, wn = (w >> 1) * 64;
  const int m0   = blockIdx.y * 128, n0 = blockIdx.x * 128;

  // staging: thread chunk flat=t*256+tid -> tile row flat>>2, col8 (flat&3)*8
  const int r0 = tid >> 2, c0 = (tid & 3) * 8;
  const u16* ga0 = A  + (size_t)(m0 + r0)      * K + c0;
  const u16* ga1 = A  + (size_t)(m0 + 64 + r0) * K + c0;
  const u16* gb0 = Bt + (size_t)(n0 + r0)      * K + c0;
  const u16* gb1 = Bt + (size_t)(n0 + 64 + r0) * K + c0;
  u16* lA0 = As +        (tid & ~63) * 8;
  u16* lA1 = As + 2048 + (tid & ~63) * 8;
  u16* lB0 = Bs +        (tid & ~63) * 8;
  u16* lB1 = Bs + 2048 + (tid & ~63) * 8;

  f32x4 acc[4][4] = {};

  for (int k0 = 0; k0 < K; k0 += 32) {
    gload_lds16(ga0 + k0, lA0);
    gload_lds16(ga1 + k0, lA1);
    gload_lds16(gb0 + k0, lB0);
    gload_lds16(gb1 + k0, lB1);
    __syncthreads();                 // drains vmcnt -> staged data visible
    short8 af[4], bfr[4];
    #pragma unroll
    for (int i = 0; i < 4; ++i)
      af[i] = *(const short8*)(As + (wm + i * 16 + l15) * 32 + lg * 8);
    #pragma unroll
    for (int j = 0; j < 4; ++j)
      bfr[j] = *(const short8*)(Bs + (wn + j * 16 + l15) * 32 + lg * 8);
    #pragma unroll
    for (int i = 0; i < 4; ++i)
      #pragma unroll
      for (int j = 0; j < 4; ++j)
        acc[i][j] = __builtin_amdgcn_mfma_f32_16x16x32_bf16(af[i], bfr[j], acc[i][j], 0, 0, 0);
    __syncthreads();                 // protect LDS from next-iter staging
  }

  #pragma unroll
  for (int j = 0; j < 4; ++j) {
    const int col = n0 + wn + j * 16 + l15;
    const float bv = bias[col];
    #pragma unroll
    for (int i = 0; i < 4; ++i) {
      #pragma unroll
      for (int r = 0; r < 4; ++r) {
        const int row = m0 + wm + i * 16 + lg * 4 + r;
        const size_t off = (size_t)row * N + col;
        float v = acc[i][j][r] + bv;
        if (EPI == 1) {
          ((float*)out)[off] = v + resid[off];
        } else if (EPI == 2) {
          float gg = 0.5f * v * (1.0f + erff(v * 0.70710678118654752f));
          ((u16*)out)[off] = f2bf(gg);
        } else {
          ((u16*)out)[off] = f2bf(v);
        }
      }
    }
  }
}

// ---------------------------------------------------------------- V transpose: qkv v-section -> vt[b][h][d][t]
__global__ __launch_bounds__(256) void vtrans_k(
    const u16* __restrict__ qkv, u16* __restrict__ vt)
{
  __shared__ u16 tile[DH_][66];
  const int tid = threadIdx.x;
  const int bid = blockIdx.x;
  const int tt = bid & 31;
  const int bh = bid >> 5;            // b*16+h
  const int b  = bh >> 4, h = bh & 15;
  const int t0 = tt * 64;
  const u16* src = qkv + (size_t)b * T_ * QKVN + 2 * E_ + h * DH_;
  #pragma unroll
  for (int it = 0; it < 8; ++it) {
    int c = it * 256 + tid;           // 2048 chunks of 4: 64 t x 32 dc
    int t = c >> 5, dc = c & 31;
    u16x4 v = *(const u16x4*)(src + (size_t)(t0 + t) * QKVN + dc * 4);
    #pragma unroll
    for (int j = 0; j < 4; ++j) tile[dc * 4 + j][t] = v[j];
  }
  __syncthreads();
  u16* dst = vt + (size_t)bh * DH_ * T_ + t0;
  #pragma unroll
  for (int it = 0; it < 8; ++it) {
    int c = it * 256 + tid;           // 128 d x 16 tc
    int d = c >> 4, tc = c & 15;
    u16x4 v;
    #pragma unroll
    for (int j = 0; j < 4; ++j) v[j] = tile[d][tc * 4 + j];
    *(u16x4*)(dst + (size_t)d * T_ + tc * 4) = v;
  }
}

// ---------------------------------------------------------------- flash attention (causal)
__global__ __launch_bounds__(256) void attn_k(
    const u16* __restrict__ qkv, const u16* __restrict__ vt, u16* __restrict__ o)
{
  const int tid  = threadIdx.x;
  const int lane = tid & 63;
  const int w    = tid >> 6;
  const int l15  = lane & 15, lg = lane >> 4;
  const int bid  = blockIdx.x;
  const int qt = bid & 31;
  const int h  = (bid >> 5) & 15;
  const int b  = bid >> 9;
  const int q0 = qt * 64 + w * 16;    // this wave's 16 q-rows

  const u16* qb  = qkv + (size_t)b * T_ * QKVN + h * DH_;
  const u16* kb  = qb + E_;
  const u16* vtb = vt + (size_t)(b * H_ + h) * DH_ * T_;

  short8 qf[4];
  {
    const u16* qr = qb + (size_t)(q0 + l15) * QKVN + lg * 8;
    #pragma unroll
    for (int d = 0; d < 4; ++d) qf[d] = *(const short8*)(qr + d * 32);
  }

  f32x4 oacc[8] = {};
  float mrow[4] = {-1e30f, -1e30f, -1e30f, -1e30f};
  float lrow[4] = {0.f, 0.f, 0.f, 0.f};

  __shared__ __align__(16) u16 plds[4][16][40];   // wave-private P, padded rows (80B)

  const float scl = 0.08838834764831845f;  // 1/sqrt(128)
  const int ntiles = (q0 + 47) >> 5;
  for (int st = 0; st < ntiles; ++st) {
    const int s0 = st * 32;
    f32x4 sc[2] = {};
    #pragma unroll
    for (int sb = 0; sb < 2; ++sb) {
      const u16* kr = kb + (size_t)(s0 + sb * 16 + l15) * QKVN + lg * 8;
      #pragma unroll
      for (int d = 0; d < 4; ++d) {
        short8 kf = *(const short8*)(kr + d * 32);
        sc[sb] = __builtin_amdgcn_mfma_f32_16x16x32_bf16(qf[d], kf, sc[sb], 0, 0, 0);
      }
    }
    const bool needmask = (s0 + 31 > q0);
    float tmax[4] = {-1e30f, -1e30f, -1e30f, -1e30f};
    #pragma unroll
    for (int sb = 0; sb < 2; ++sb)
      #pragma unroll
      for (int r = 0; r < 4; ++r) {
        float v = sc[sb][r] * scl;
        if (needmask) {
          int s = s0 + sb * 16 + l15;
          int q = q0 + lg * 4 + r;
          if (s > q) v = -1e30f;
        }
        sc[sb][r] = v;
        tmax[r] = fmaxf(tmax[r], v);
      }
    #pragma unroll
    for (int r = 0; r < 4; ++r) {
      #pragma unroll
      for (int m = 1; m < 16; m <<= 1) tmax[r] = fmaxf(tmax[r], __shfl_xor(tmax[r], m));
    }
    float alpha[4], rsum[4];
    #pragma unroll
    for (int r = 0; r < 4; ++r) {
      float mn = fmaxf(mrow[r], tmax[r]);
      alpha[r] = __expf(mrow[r] - mn);
      mrow[r] = mn;
      rsum[r] = 0.f;
    }
    #pragma unroll
    for (int sb = 0; sb < 2; ++sb)
      #pragma unroll
      for (int r = 0; r < 4; ++r) {
        float p = __expf(sc[sb][r] - mrow[r]);
        rsum[r] += p;
        plds[w][lg * 4 + r][sb * 16 + l15] = f2bf(p);
      }
    #pragma unroll
    for (int r = 0; r < 4; ++r) {
      #pragma unroll
      for (int m = 1; m < 16; m <<= 1) rsum[r] += __shfl_xor(rsum[r], m);
      lrow[r] = lrow[r] * alpha[r] + rsum[r];
    }
    #pragma unroll
    for (int i = 0; i < 8; ++i)
      #pragma unroll
      for (int r = 0; r < 4; ++r) oacc[i][r] *= alpha[r];
    // PV: A = P (from LDS), B = V via vt[d][t] (contiguous along s)
    short8 pf = *(const short8*)(&plds[w][l15][lg * 8]);
    #pragma unroll
    for (int d = 0; d < 8; ++d) {
      const u16* vr = vtb + (size_t)(d * 16 + l15) * T_ + s0 + lg * 8;
      short8 vf = *(const short8*)vr;
      oacc[d] = __builtin_amdgcn_mfma_f32_16x16x32_bf16(pf, vf, oacc[d], 0, 0, 0);
    }
  }
  float inv[4];
  #pragma unroll
  for (int r = 0; r < 4; ++r) inv[r] = 1.0f / lrow[r];
  u16* ob = o + (size_t)(b * T_ + q0) * E_ + h * DH_;
  #pragma unroll
  for (int d = 0; d < 8; ++d)
    #pragma unroll
    for (int r = 0; r < 4; ++r)
      ob[(size_t)(lg * 4 + r) * E_ + d * 16 + l15] = f2bf(oacc[d][r] * inv[r]);
}

// ---------------------------------------------------------------- launch
extern "C" void kernel_launch(void* const* d_in, const int* in_sizes, int n_in,
                              void* d_out, int out_size, void* d_ws, size_t ws_size,
                              hipStream_t stream)
{
  const float* x  = (const float*)d_in[0];
  const float* wq = (const float*)d_in[1];
  const float* bq = (const float*)d_in[2];
  const float* wk = (const float*)d_in[3];
  const float* bk = (const float*)d_in[4];
  const float* wv = (const float*)d_in[5];
  const float* bv = (const float*)d_in[6];
  const float* wo = (const float*)d_in[7];
  const float* bo = (const float*)d_in[8];
  const float* w1 = (const float*)d_in[9];
  const float* b1 = (const float*)d_in[10];
  const float* w2 = (const float*)d_in[11];
  const float* b2 = (const float*)d_in[12];
  const float* g1 = (const float*)d_in[13];
  const float* g2 = (const float*)d_in[14];
  float* xout = (float*)d_out;

  if (ws_size < 201351168u) return;   // need ~192 MB scratch

  char* ws = (char*)d_ws;
  u16*   wqkv_t = (u16*)(ws + 0);            // 25,165,824
  u16*   h1     = (u16*)(ws + 25165824);     // 16,777,216
  u16*   qkv    = (u16*)(ws + 41943040);     // 50,331,648
  u16*   vt     = (u16*)(ws + 92274688);     // 16,777,216
  u16*   o_     = (u16*)(ws + 109051904);    // 16,777,216
  u16*   wo_t   = (u16*)(ws + 125829120);    //  8,388,608
  u16*   w1_t   = (u16*)(ws + 134217728);    // 33,554,432
  u16*   w2_t   = (u16*)(ws + 167772160);    // 33,554,432
  float* bqkv   = (float*)(ws + 201326592);  //     24,576
  u16*   u_     = (u16*)(ws + 0);            // 67,108,864 (aliases dead wqkv_t/h1/qkv-prefix)
  u16*   h2     = vt;                        // aliases dead vt
  float* x2     = xout;                      // d_out doubles as residual-2 buffer

  // weight prep (bf16, transposed to [N][K])
  prep_qkv<<<(QKVN * E_) / 256, 256, 0, stream>>>(wq, wk, wv, bq, bk, bv, wqkv_t, bqkv);
  prep_t<<<(E_ * E_) / 256, 256, 0, stream>>>(wo, wo_t, 11, E_);          // [2048][2048]
  prep_t<<<(4 * E_ * E_) / 256, 256, 0, stream>>>(w1, w1_t, 11, 4 * E_);  // [8192][2048]
  prep_t<<<(4 * E_ * E_) / 256, 256, 0, stream>>>(w2, w2_t, 13, E_);      // [2048][8192]

  rmsnorm_k<<<NTOK, 256, 0, stream>>>(x, g1, h1);
  gemm_bt<0><<<dim3(QKVN / 128, NTOK / 128), 256, 0, stream>>>(h1, wqkv_t, bqkv, nullptr, qkv, NTOK, QKVN, E_);
  vtrans_k<<<B_ * H_ * (T_ / 64), 256, 0, stream>>>(qkv, vt);
  attn_k<<<B_ * H_ * (T_ / 64), 256, 0, stream>>>(qkv, vt, o_);
  gemm_bt<1><<<dim3(E_ / 128, NTOK / 128), 256, 0, stream>>>(o_, wo_t, bo, x, x2, NTOK, E_, E_);
  rmsnorm_k<<<NTOK, 256, 0, stream>>>(x2, g2, h2);
  gemm_bt<2><<<dim3(4 * E_ / 128, NTOK / 128), 256, 0, stream>>>(h2, w1_t, b1, nullptr, u_, NTOK, 4 * E_, E_);
  gemm_bt<1><<<dim3(E_ / 128, NTOK / 128), 256, 0, stream>>>(u_, w2_t, b2, x2, xout, NTOK, E_, 4 * E_);
}

// Round 2
// 1096.463 us; speedup vs baseline: 1.2385x; 1.2385x over previous
//
#include <hip/hip_runtime.h>
#include <hip/hip_bf16.h>

typedef unsigned short u16;
typedef unsigned int   u32;
typedef __attribute__((ext_vector_type(8))) short short8;
typedef __attribute__((ext_vector_type(4))) float f32x4;
typedef __attribute__((ext_vector_type(4))) unsigned short u16x4;

#define E_    2048
#define H_    16
#define DH_   128
#define B_    2
#define T_    2048
#define NTOK  4096      // B*T
#define QKVN  6144      // 3*E

__device__ __forceinline__ u16 f2bf(float f) {
  union { float f; u32 u; } v; v.f = f;
  u32 r = (v.u + 0x7FFFu + ((v.u >> 16) & 1u)) >> 16;
  return (u16)r;
}

// ---------------------------------------------------------------- prep kernels

// wqkv_t[n][e] (bf16, n = sec*2048 + h*128 + d) from wq/wk/wv[h][e][d]; bias concat
__global__ __launch_bounds__(256) void prep_qkv(
    const float* __restrict__ wq, const float* __restrict__ wk, const float* __restrict__ wv,
    const float* __restrict__ bq, const float* __restrict__ bk, const float* __restrict__ bv,
    u16* __restrict__ wt, float* __restrict__ bias)
{
  size_t idx = (size_t)blockIdx.x * 256 + threadIdx.x;   // over 6144*2048
  int n = (int)(idx >> 11);
  int e = (int)(idx & 2047);
  int sec = n >> 11;
  int hd  = n & 2047;
  const float* w = (sec == 0) ? wq : (sec == 1) ? wk : wv;
  float v = w[(size_t)(hd >> 7) * (E_ * DH_) + (size_t)e * DH_ + (hd & 127)];
  wt[idx] = f2bf(v);
  if (idx < QKVN) {
    int s2 = (int)(idx >> 11);
    const float* bb = (s2 == 0) ? bq : (s2 == 1) ? bk : bv;
    bias[idx] = bb[idx & 2047];
  }
}

// out[n][k] = bf16(in[k][n]); K = 1<<kshift
__global__ __launch_bounds__(256) void prep_t(
    const float* __restrict__ in, u16* __restrict__ out, int kshift, int N)
{
  size_t idx = (size_t)blockIdx.x * 256 + threadIdx.x;
  size_t n = idx >> kshift;
  size_t k = idx & ((1u << kshift) - 1u);
  out[idx] = f2bf(in[k * (size_t)N + n]);
}

// ---------------------------------------------------------------- rmsnorm (fp32 in, bf16 out)
__global__ __launch_bounds__(256) void rmsnorm_k(
    const float* __restrict__ x, const float* __restrict__ g, u16* __restrict__ o)
{
  const int row = blockIdx.x;
  const float4* xr = (const float4*)(x + (size_t)row * E_);
  const float4* gr = (const float4*)g;
  const int tid = threadIdx.x;
  float4 a0 = xr[tid], a1 = xr[tid + 256];
  float s = a0.x*a0.x + a0.y*a0.y + a0.z*a0.z + a0.w*a0.w
          + a1.x*a1.x + a1.y*a1.y + a1.z*a1.z + a1.w*a1.w;
  #pragma unroll
  for (int m = 1; m < 64; m <<= 1) s += __shfl_xor(s, m);
  __shared__ float wsum[4];
  if ((tid & 63) == 0) wsum[tid >> 6] = s;
  __syncthreads();
  float tot = wsum[0] + wsum[1] + wsum[2] + wsum[3];
  float rinv = rsqrtf(tot * (1.0f / E_) + 1e-8f);
  float4 g0 = gr[tid], g1 = gr[tid + 256];
  u16x4 o0, o1;
  o0[0] = f2bf(a0.x * g0.x * rinv); o0[1] = f2bf(a0.y * g0.y * rinv);
  o0[2] = f2bf(a0.z * g0.z * rinv); o0[3] = f2bf(a0.w * g0.w * rinv);
  o1[0] = f2bf(a1.x * g1.x * rinv); o1[1] = f2bf(a1.y * g1.y * rinv);
  o1[2] = f2bf(a1.z * g1.z * rinv); o1[3] = f2bf(a1.w * g1.w * rinv);
  u16x4* orow = (u16x4*)(o + (size_t)row * E_);
  orow[tid] = o0;
  orow[tid + 256] = o1;
}

// ---------------------------------------------------------------- GEMM (m97 structure)
__device__ __forceinline__ void gload_lds16(const void* g, u16* lds_base) {
  __builtin_amdgcn_global_load_lds(
      (const __attribute__((address_space(1))) u32*)g,
      (__attribute__((address_space(3))) u32*)lds_base, 16, 0, 0);
}

// EPI: 0 = bf16 out (+bias), 1 = f32 out (+bias+resid), 2 = bf16 out (+bias, exact GELU)
template<int EPI>
__global__ __launch_bounds__(256)
void gemm_bt(const u16* __restrict__ A, const u16* __restrict__ Bt,
             const float* __restrict__ bias, const float* __restrict__ resid,
             void* __restrict__ out, int M, int N, int K)
{
  __shared__ __align__(16) u16 As[128 * 32];
  __shared__ __align__(16) u16 Bs[128 * 32];
  const int tid  = threadIdx.x;
  const int lane = tid & 63;
  const int l15  = lane & 15, lg = lane >> 4;
  const int w    = tid >> 6;
  const int wm   = (w & 1) * 64, wn = (w >> 1) * 64;
  const int m0   = blockIdx.y * 128, n0 = blockIdx.x * 128;

  const int r0 = tid >> 2, c0 = (tid & 3) * 8;
  const u16* ga0 = A  + (size_t)(m0 + r0)      * K + c0;
  const u16* ga1 = A  + (size_t)(m0 + 64 + r0) * K + c0;
  const u16* gb0 = Bt + (size_t)(n0 + r0)      * K + c0;
  const u16* gb1 = Bt + (size_t)(n0 + 64 + r0) * K + c0;
  u16* lA0 = As +        (tid & ~63) * 8;
  u16* lA1 = As + 2048 + (tid & ~63) * 8;
  u16* lB0 = Bs +        (tid & ~63) * 8;
  u16* lB1 = Bs + 2048 + (tid & ~63) * 8;

  f32x4 acc[4][4] = {};

  for (int k0 = 0; k0 < K; k0 += 32) {
    gload_lds16(ga0 + k0, lA0);
    gload_lds16(ga1 + k0, lA1);
    gload_lds16(gb0 + k0, lB0);
    gload_lds16(gb1 + k0, lB1);
    __syncthreads();
    short8 af[4], bfr[4];
    #pragma unroll
    for (int i = 0; i < 4; ++i)
      af[i] = *(const short8*)(As + (wm + i * 16 + l15) * 32 + lg * 8);
    #pragma unroll
    for (int j = 0; j < 4; ++j)
      bfr[j] = *(const short8*)(Bs + (wn + j * 16 + l15) * 32 + lg * 8);
    #pragma unroll
    for (int i = 0; i < 4; ++i)
      #pragma unroll
      for (int j = 0; j < 4; ++j)
        acc[i][j] = __builtin_amdgcn_mfma_f32_16x16x32_bf16(af[i], bfr[j], acc[i][j], 0, 0, 0);
    __syncthreads();
  }

  #pragma unroll
  for (int j = 0; j < 4; ++j) {
    const int col = n0 + wn + j * 16 + l15;
    const float bv = bias[col];
    #pragma unroll
    for (int i = 0; i < 4; ++i) {
      #pragma unroll
      for (int r = 0; r < 4; ++r) {
        const int row = m0 + wm + i * 16 + lg * 4 + r;
        const size_t off = (size_t)row * N + col;
        float v = acc[i][j][r] + bv;
        if (EPI == 1) {
          ((float*)out)[off] = v + resid[off];
        } else if (EPI == 2) {
          float gg = 0.5f * v * (1.0f + erff(v * 0.70710678118654752f));
          ((u16*)out)[off] = f2bf(gg);
        } else {
          ((u16*)out)[off] = f2bf(v);
        }
      }
    }
  }
}

// ---------------------------------------------------------------- V transpose: qkv v-section -> vt[b][h][d][t]
__global__ __launch_bounds__(256) void vtrans_k(
    const u16* __restrict__ qkv, u16* __restrict__ vt)
{
  __shared__ u16 tile[DH_][66];
  const int tid = threadIdx.x;
  const int bid = blockIdx.x;
  const int tt = bid & 31;
  const int bh = bid >> 5;            // b*16+h
  const int b  = bh >> 4, h = bh & 15;
  const int t0 = tt * 64;
  const u16* src = qkv + (size_t)b * T_ * QKVN + 2 * E_ + h * DH_;
  #pragma unroll
  for (int it = 0; it < 8; ++it) {
    int c = it * 256 + tid;           // 2048 chunks of 4: 64 t x 32 dc
    int t = c >> 5, dc = c & 31;
    u16x4 v = *(const u16x4*)(src + (size_t)(t0 + t) * QKVN + dc * 4);
    #pragma unroll
    for (int j = 0; j < 4; ++j) tile[dc * 4 + j][t] = v[j];
  }
  __syncthreads();
  u16* dst = vt + (size_t)bh * DH_ * T_ + t0;
  #pragma unroll
  for (int it = 0; it < 8; ++it) {
    int c = it * 256 + tid;           // 128 d x 16 tc
    int d = c >> 4, tc = c & 15;
    u16x4 v;
    #pragma unroll
    for (int j = 0; j < 4; ++j) v[j] = tile[d][tc * 4 + j];
    *(u16x4*)(dst + (size_t)d * T_ + tc * 4) = v;
  }
}

// ---------------------------------------------------------------- flash attention (causal)
// 512 blocks: (b, h, qt) with qt reversed (heavy blocks dispatch first).
// Block: 128 q-rows, 4 waves x 32 rows. K-tile [64][128] + V^T-tile [128][64]
// staged in LDS via global_load_lds, XOR-swizzled (chunk ^= row&7) against
// the 32-way bank conflict of 256B/128B row strides.
__global__ __launch_bounds__(256) void attn_k(
    const u16* __restrict__ qkv, const u16* __restrict__ vt, u16* __restrict__ o)
{
  const int tid  = threadIdx.x;
  const int lane = tid & 63;
  const int w    = tid >> 6;
  const int l15  = lane & 15, lg = lane >> 4;
  const int bid  = blockIdx.x;
  const int qt = 15 - (bid & 15);
  const int h  = (bid >> 4) & 15;
  const int b  = bid >> 8;
  const int Q0 = qt * 128;
  const int qw = Q0 + w * 32;         // this wave's 32 q-rows

  __shared__ __align__(16) u16 Ks[64 * 128];   // [s][dh], chunk-swizzled
  __shared__ __align__(16) u16 Vs[128 * 64];   // [dh][s], chunk-swizzled
  __shared__ __align__(16) u16 Ps[4][32][72];  // per-wave P [q][s], padded

  const u16* qb  = qkv + (size_t)b * T_ * QKVN + h * DH_;
  const u16* kb  = qb + E_;
  const u16* vtb = vt + (size_t)(b * H_ + h) * DH_ * T_;

  // Q fragments: 2 qi x 4 k-steps (lane l15 = q-row, lg*8 = dh offset)
  short8 qf[2][4];
  #pragma unroll
  for (int qi = 0; qi < 2; ++qi)
    #pragma unroll
    for (int kk = 0; kk < 4; ++kk)
      qf[qi][kk] = *(const short8*)(qb + (size_t)(qw + qi * 16 + l15) * QKVN + kk * 32 + lg * 8);

  f32x4 oacc[2][8] = {};
  float m_[2][4], l_[2][4];
  #pragma unroll
  for (int qi = 0; qi < 2; ++qi)
    #pragma unroll
    for (int r = 0; r < 4; ++r) { m_[qi][r] = -1e30f; l_[qi][r] = 0.f; }

  const int xr = l15 & 7;
  const float scl = 0.08838834764831845f;   // 1/sqrt(128)
  const int nt = Q0 / 64 + 2;
  const int qmaxw = qw + 31;
  const int wub = (tid & ~63);              // wave-uniform LDS chunk base

  for (int st = 0; st < nt; ++st) {
    const int s0 = st * 64;
    // stage K-tile: 1024 16B chunks; source chunk p^(r&7) -> stored pos p
    #pragma unroll
    for (int i = 0; i < 4; ++i) {
      int f = i * 256 + tid;
      int r = f >> 4, p = f & 15, c = p ^ (r & 7);
      gload_lds16(kb + (size_t)(s0 + r) * QKVN + c * 8, Ks + (size_t)(i * 256 + wub) * 8);
    }
    // stage V^T-tile: 1024 16B chunks (8 per d-row)
    #pragma unroll
    for (int i = 0; i < 4; ++i) {
      int f = i * 256 + tid;
      int d = f >> 3, p = f & 7, c = p ^ (d & 7);
      gload_lds16(vtb + (size_t)d * T_ + s0 + c * 8, Vs + (size_t)(i * 256 + wub) * 8);
    }
    __syncthreads();                         // drains vmcnt: tiles visible

    if (s0 <= qmaxw) {
      // ---- QK^T: S[32 q][64 s]
      f32x4 sc[2][4] = {};
      #pragma unroll
      for (int sj = 0; sj < 4; ++sj) {
        const int row = sj * 16 + l15;
        #pragma unroll
        for (int kk = 0; kk < 4; ++kk) {
          short8 kfr = *(const short8*)(Ks + row * 128 + (((kk * 4 + lg) ^ xr) * 8));
          sc[0][sj] = __builtin_amdgcn_mfma_f32_16x16x32_bf16(qf[0][kk], kfr, sc[0][sj], 0, 0, 0);
          sc[1][sj] = __builtin_amdgcn_mfma_f32_16x16x32_bf16(qf[1][kk], kfr, sc[1][sj], 0, 0, 0);
        }
      }
      // ---- scale + causal mask
      const bool needmask = (s0 + 63 > qw);
      #pragma unroll
      for (int qi = 0; qi < 2; ++qi)
        #pragma unroll
        for (int sj = 0; sj < 4; ++sj)
          #pragma unroll
          for (int r = 0; r < 4; ++r) {
            float v = sc[qi][sj][r] * scl;
            if (needmask) {
              int s = s0 + sj * 16 + l15;
              int q = qw + qi * 16 + lg * 4 + r;
              if (s > q) v = -1e30f;
            }
            sc[qi][sj][r] = v;
          }
      // ---- online softmax
      #pragma unroll
      for (int qi = 0; qi < 2; ++qi) {
        float tmax[4], alpha[4], rsum[4];
        #pragma unroll
        for (int r = 0; r < 4; ++r)
          tmax[r] = fmaxf(fmaxf(sc[qi][0][r], sc[qi][1][r]), fmaxf(sc[qi][2][r], sc[qi][3][r]));
        #pragma unroll
        for (int r = 0; r < 4; ++r)
          #pragma unroll
          for (int m = 1; m < 16; m <<= 1) tmax[r] = fmaxf(tmax[r], __shfl_xor(tmax[r], m));
        #pragma unroll
        for (int r = 0; r < 4; ++r) {
          float mn = fmaxf(m_[qi][r], tmax[r]);
          alpha[r] = __expf(m_[qi][r] - mn);
          m_[qi][r] = mn;
          rsum[r] = 0.f;
        }
        #pragma unroll
        for (int sj = 0; sj < 4; ++sj)
          #pragma unroll
          for (int r = 0; r < 4; ++r) {
            float p = __expf(sc[qi][sj][r] - m_[qi][r]);
            rsum[r] += p;
            Ps[w][qi * 16 + lg * 4 + r][sj * 16 + l15] = f2bf(p);
          }
        #pragma unroll
        for (int r = 0; r < 4; ++r) {
          #pragma unroll
          for (int m = 1; m < 16; m <<= 1) rsum[r] += __shfl_xor(rsum[r], m);
          l_[qi][r] = l_[qi][r] * alpha[r] + rsum[r];
        }
        #pragma unroll
        for (int dj = 0; dj < 8; ++dj)
          #pragma unroll
          for (int r = 0; r < 4; ++r) oacc[qi][dj][r] *= alpha[r];
      }
      // ---- PV: O += P[32x64] * V[64x128]
      asm volatile("s_waitcnt lgkmcnt(0)" ::: "memory");
      __builtin_amdgcn_sched_barrier(0);
      #pragma unroll
      for (int ks = 0; ks < 2; ++ks) {
        short8 pf0 = *(const short8*)(&Ps[w][l15][ks * 32 + lg * 8]);
        short8 pf1 = *(const short8*)(&Ps[w][16 + l15][ks * 32 + lg * 8]);
        #pragma unroll
        for (int dj = 0; dj < 8; ++dj) {
          const int row = dj * 16 + l15;
          short8 vfr = *(const short8*)(Vs + row * 64 + (((ks * 4 + lg) ^ xr) * 8));
          oacc[0][dj] = __builtin_amdgcn_mfma_f32_16x16x32_bf16(pf0, vfr, oacc[0][dj], 0, 0, 0);
          oacc[1][dj] = __builtin_amdgcn_mfma_f32_16x16x32_bf16(pf1, vfr, oacc[1][dj], 0, 0, 0);
        }
      }
    }
    __syncthreads();                         // protect tiles before next staging
  }

  float inv[2][4];
  #pragma unroll
  for (int qi = 0; qi < 2; ++qi)
    #pragma unroll
    for (int r = 0; r < 4; ++r) inv[qi][r] = 1.0f / l_[qi][r];
  u16* ob = o + (size_t)(b * T_ + qw) * E_ + h * DH_;
  #pragma unroll
  for (int qi = 0; qi < 2; ++qi)
    #pragma unroll
    for (int dj = 0; dj < 8; ++dj)
      #pragma unroll
      for (int r = 0; r < 4; ++r)
        ob[(size_t)(qi * 16 + lg * 4 + r) * E_ + dj * 16 + l15] = f2bf(oacc[qi][dj][r] * inv[qi][r]);
}

// ---------------------------------------------------------------- launch
extern "C" void kernel_launch(void* const* d_in, const int* in_sizes, int n_in,
                              void* d_out, int out_size, void* d_ws, size_t ws_size,
                              hipStream_t stream)
{
  const float* x  = (const float*)d_in[0];
  const float* wq = (const float*)d_in[1];
  const float* bq = (const float*)d_in[2];
  const float* wk = (const float*)d_in[3];
  const float* bk = (const float*)d_in[4];
  const float* wv = (const float*)d_in[5];
  const float* bv = (const float*)d_in[6];
  const float* wo = (const float*)d_in[7];
  const float* bo = (const float*)d_in[8];
  const float* w1 = (const float*)d_in[9];
  const float* b1 = (const float*)d_in[10];
  const float* w2 = (const float*)d_in[11];
  const float* b2 = (const float*)d_in[12];
  const float* g1 = (const float*)d_in[13];
  const float* g2 = (const float*)d_in[14];
  float* xout = (float*)d_out;

  if (ws_size < 201351168u) return;   // need ~192 MB scratch

  char* ws = (char*)d_ws;
  u16*   wqkv_t = (u16*)(ws + 0);            // 25,165,824
  u16*   h1     = (u16*)(ws + 25165824);     // 16,777,216
  u16*   qkv    = (u16*)(ws + 41943040);     // 50,331,648
  u16*   vt     = (u16*)(ws + 92274688);     // 16,777,216
  u16*   o_     = (u16*)(ws + 109051904);    // 16,777,216
  u16*   wo_t   = (u16*)(ws + 125829120);    //  8,388,608
  u16*   w1_t   = (u16*)(ws + 134217728);    // 33,554,432
  u16*   w2_t   = (u16*)(ws + 167772160);    // 33,554,432
  float* bqkv   = (float*)(ws + 201326592);  //     24,576
  u16*   u_     = (u16*)(ws + 0);            // 67,108,864 (aliases dead wqkv_t/h1/qkv-prefix)
  u16*   h2     = vt;                        // aliases dead vt
  float* x2     = xout;                      // d_out doubles as residual-2 buffer

  prep_qkv<<<(QKVN * E_) / 256, 256, 0, stream>>>(wq, wk, wv, bq, bk, bv, wqkv_t, bqkv);
  prep_t<<<(E_ * E_) / 256, 256, 0, stream>>>(wo, wo_t, 11, E_);
  prep_t<<<(4 * E_ * E_) / 256, 256, 0, stream>>>(w1, w1_t, 11, 4 * E_);
  prep_t<<<(4 * E_ * E_) / 256, 256, 0, stream>>>(w2, w2_t, 13, E_);

  rmsnorm_k<<<NTOK, 256, 0, stream>>>(x, g1, h1);
  gemm_bt<0><<<dim3(QKVN / 128, NTOK / 128), 256, 0, stream>>>(h1, wqkv_t, bqkv, nullptr, qkv, NTOK, QKVN, E_);
  vtrans_k<<<B_ * H_ * (T_ / 64), 256, 0, stream>>>(qkv, vt);
  attn_k<<<B_ * H_ * (T_ / 16 / 8), 256, 0, stream>>>(qkv, vt, o_);   // 512 blocks
  gemm_bt<1><<<dim3(E_ / 128, NTOK / 128), 256, 0, stream>>>(o_, wo_t, bo, x, x2, NTOK, E_, E_);
  rmsnorm_k<<<NTOK, 256, 0, stream>>>(x2, g2, h2);
  gemm_bt<2><<<dim3(4 * E_ / 128, NTOK / 128), 256, 0, stream>>>(h2, w1_t, b1, nullptr, u_, NTOK, 4 * E_, E_);
  gemm_bt<1><<<dim3(E_ / 128, NTOK / 128), 256, 0, stream>>>(u_, w2_t, b2, x2, xout, NTOK, E_, 4 * E_);
}

// Round 3
// 1000.385 us; speedup vs baseline: 1.3575x; 1.0960x over previous
//
#include <hip/hip_runtime.h>
#include <hip/hip_bf16.h>

typedef unsigned short u16;
typedef unsigned int   u32;
typedef __attribute__((ext_vector_type(8))) short short8;
typedef __attribute__((ext_vector_type(4))) float f32x4;
typedef __attribute__((ext_vector_type(4))) unsigned short u16x4;

#define E_    2048
#define H_    16
#define DH_   128
#define B_    2
#define T_    2048
#define NTOK  4096      // B*T
#define QKVN  6144      // 3*E

__device__ __forceinline__ u16 f2bf(float f) {
  union { float f; u32 u; } v; v.f = f;
  u32 r = (v.u + 0x7FFFu + ((v.u >> 16) & 1u)) >> 16;
  return (u16)r;
}

// ---------------------------------------------------------------- prep kernels

__global__ __launch_bounds__(256) void prep_qkv(
    const float* __restrict__ wq, const float* __restrict__ wk, const float* __restrict__ wv,
    const float* __restrict__ bq, const float* __restrict__ bk, const float* __restrict__ bv,
    u16* __restrict__ wt, float* __restrict__ bias)
{
  size_t idx = (size_t)blockIdx.x * 256 + threadIdx.x;   // over 6144*2048
  int n = (int)(idx >> 11);
  int e = (int)(idx & 2047);
  int sec = n >> 11;
  int hd  = n & 2047;
  const float* w = (sec == 0) ? wq : (sec == 1) ? wk : wv;
  float v = w[(size_t)(hd >> 7) * (E_ * DH_) + (size_t)e * DH_ + (hd & 127)];
  wt[idx] = f2bf(v);
  if (idx < QKVN) {
    int s2 = (int)(idx >> 11);
    const float* bb = (s2 == 0) ? bq : (s2 == 1) ? bk : bv;
    bias[idx] = bb[idx & 2047];
  }
}

__global__ __launch_bounds__(256) void prep_t(
    const float* __restrict__ in, u16* __restrict__ out, int kshift, int N)
{
  size_t idx = (size_t)blockIdx.x * 256 + threadIdx.x;
  size_t n = idx >> kshift;
  size_t k = idx & ((1u << kshift) - 1u);
  out[idx] = f2bf(in[k * (size_t)N + n]);
}

// ---------------------------------------------------------------- rmsnorm
__global__ __launch_bounds__(256) void rmsnorm_k(
    const float* __restrict__ x, const float* __restrict__ g, u16* __restrict__ o)
{
  const int row = blockIdx.x;
  const float4* xr = (const float4*)(x + (size_t)row * E_);
  const float4* gr = (const float4*)g;
  const int tid = threadIdx.x;
  float4 a0 = xr[tid], a1 = xr[tid + 256];
  float s = a0.x*a0.x + a0.y*a0.y + a0.z*a0.z + a0.w*a0.w
          + a1.x*a1.x + a1.y*a1.y + a1.z*a1.z + a1.w*a1.w;
  #pragma unroll
  for (int m = 1; m < 64; m <<= 1) s += __shfl_xor(s, m);
  __shared__ float wsum[4];
  if ((tid & 63) == 0) wsum[tid >> 6] = s;
  __syncthreads();
  float tot = wsum[0] + wsum[1] + wsum[2] + wsum[3];
  float rinv = rsqrtf(tot * (1.0f / E_) + 1e-8f);
  float4 g0 = gr[tid], g1 = gr[tid + 256];
  u16x4 o0, o1;
  o0[0] = f2bf(a0.x * g0.x * rinv); o0[1] = f2bf(a0.y * g0.y * rinv);
  o0[2] = f2bf(a0.z * g0.z * rinv); o0[3] = f2bf(a0.w * g0.w * rinv);
  o1[0] = f2bf(a1.x * g1.x * rinv); o1[1] = f2bf(a1.y * g1.y * rinv);
  o1[2] = f2bf(a1.z * g1.z * rinv); o1[3] = f2bf(a1.w * g1.w * rinv);
  u16x4* orow = (u16x4*)(o + (size_t)row * E_);
  orow[tid] = o0;
  orow[tid + 256] = o1;
}

// ---------------------------------------------------------------- GEMM: 3-buffer counted-vmcnt phase pipeline
__device__ __forceinline__ void gload_lds16(const void* g, u16* lds_base) {
  __builtin_amdgcn_global_load_lds(
      (const __attribute__((address_space(1))) u32*)g,
      (__attribute__((address_space(3))) u32*)lds_base, 16, 0, 0);
}

// BK=32. 512 threads = 8 waves (2 row-halves x 4 col-quarters).
// BM=256: wave tile 128x64 (MR=8), 2 phases/K-tile, 4 stage-loads/thread/tile.
// BM=128: wave tile 64x64 (MR=4), 1 phase/K-tile, 3 stage-loads/thread/tile.
// LDS = 3 K-tile buffers; stage target (i+2)%3 never overlaps read buffer i%3.
// EPI: 0 = bf16 out (+bias), 1 = f32 out (+bias+resid), 2 = bf16 out (+bias, exact GELU)
template<int BM, int BN, int EPI>
__global__ __launch_bounds__(512, 2)
void gemm3(const u16* __restrict__ A, const u16* __restrict__ Bt,
           const float* __restrict__ bias, const float* __restrict__ resid,
           void* __restrict__ out, int M, int N, int K)
{
  constexpr int WROWS = BM / 2;          // 128 or 64
  constexpr int WCOLS = BN / 4;          // 64
  constexpr int MR    = WROWS / 16;      // 8 or 4
  constexpr int BUF   = (BM + BN) * 32;  // u16 per K-tile buffer
  constexpr int BCH   = BM * 4;          // chunk index where B region starts
  __shared__ __align__(16) u16 sh[3 * BUF];

  const int tid  = threadIdx.x;
  const int lane = tid & 63;
  const int l15  = lane & 15, lg = lane >> 4;
  const int w    = tid >> 6;
  const int wm   = w >> 2;               // 0..1
  const int wn   = w & 3;                // 0..3

  // XCD-aware bijective block swizzle (grid sizes here are all %8==0)
  const int nbx = N / BN;
  const int nwg = nbx * (M / BM);
  const int q8  = nwg >> 3;
  const int sid = (blockIdx.x & 7) * q8 + (blockIdx.x >> 3);
  const int m0  = (sid / nbx) * BM;
  const int n0  = (sid % nbx) * BN;

  // staging source pointers: thread fetches chunk (row = tid>>2, col16B = tid&3)
  const int r0 = tid >> 2, c0 = (tid & 3) * 8;
  const u16* gA  = A  + (size_t)(m0 + r0) * K + c0;
  const u16* gB  = Bt + (size_t)(n0 + r0) * K + c0;
  const u16* gA2 = gA + (size_t)128 * K;       // BM==256 only
  const u16* gB2 = gB + (size_t)128 * K;
  // wave-uniform LDS chunk bases (u16 offsets)
  const int wub = (tid & ~63) * 8;

  f32x4 acc[MR][4] = {};
  const int NT = K >> 5;

  // ---- prologue: fully stage tiles 0 and 1
  #pragma unroll
  for (int t = 0; t < 2; ++t) {
    u16* wb = sh + t * BUF;
    const int kS = t * 32;
    if constexpr (BM == 256) {
      gload_lds16(gA  + kS, wb + wub);
      gload_lds16(gA2 + kS, wb + 512 * 8 + wub);
      gload_lds16(gB  + kS, wb + 1024 * 8 + wub);
      gload_lds16(gB2 + kS, wb + 1536 * 8 + wub);
    } else {
      gload_lds16(gA  + kS, wb + wub);
      gload_lds16(gB  + kS, wb + 512 * 8 + wub);
      gload_lds16(gB2 + kS, wb + 1024 * 8 + wub);
    }
  }
  if constexpr (BM == 256) asm volatile("s_waitcnt vmcnt(4)" ::: "memory");
  else                     asm volatile("s_waitcnt vmcnt(3)" ::: "memory");
  __builtin_amdgcn_s_barrier();
  __builtin_amdgcn_sched_barrier(0);

  int b0 = 0, b2 = 2;
  #pragma unroll 1
  for (int i = 0; i < NT; ++i) {
    const u16* rb = sh + b0 * BUF;
    u16* wb = sh + b2 * BUF;
    const bool st = (i + 2 < NT);
    const int kS = (i + 2) << 5;
    short8 af[4], bf[4];

    if constexpr (BM == 256) {
      // ---------- phase 0: B frags + A m0-3; stage A-low, B-low of tile i+2
      #pragma unroll
      for (int n = 0; n < 4; ++n)
        bf[n] = *(const short8*)(rb + BM * 32 + (wn * WCOLS + n * 16 + l15) * 32 + lg * 8);
      #pragma unroll
      for (int m = 0; m < 4; ++m)
        af[m] = *(const short8*)(rb + (wm * WROWS + m * 16 + l15) * 32 + lg * 8);
      if (st) {
        gload_lds16(gA + kS, wb + wub);
        gload_lds16(gB + kS, wb + 1024 * 8 + wub);
      }
      __builtin_amdgcn_s_barrier();
      asm volatile("s_waitcnt lgkmcnt(0)" ::: "memory");
      __builtin_amdgcn_sched_barrier(0);
      __builtin_amdgcn_s_setprio(1);
      #pragma unroll
      for (int m = 0; m < 4; ++m)
        #pragma unroll
        for (int n = 0; n < 4; ++n)
          acc[m][n] = __builtin_amdgcn_mfma_f32_16x16x32_bf16(af[m], bf[n], acc[m][n], 0, 0, 0);
      __builtin_amdgcn_s_setprio(0);
      __builtin_amdgcn_s_barrier();
      __builtin_amdgcn_sched_barrier(0);
      // ---------- phase 1: A m4-7; stage A-high, B-high of tile i+2
      #pragma unroll
      for (int m = 0; m < 4; ++m)
        af[m] = *(const short8*)(rb + (wm * WROWS + (4 + m) * 16 + l15) * 32 + lg * 8);
      if (st) {
        gload_lds16(gA2 + kS, wb + 512 * 8 + wub);
        gload_lds16(gB2 + kS, wb + 1536 * 8 + wub);
      }
      __builtin_amdgcn_s_barrier();
      asm volatile("s_waitcnt lgkmcnt(0)" ::: "memory");
      __builtin_amdgcn_sched_barrier(0);
      __builtin_amdgcn_s_setprio(1);
      #pragma unroll
      for (int m = 0; m < 4; ++m)
        #pragma unroll
        for (int n = 0; n < 4; ++n)
          acc[4 + m][n] = __builtin_amdgcn_mfma_f32_16x16x32_bf16(af[m], bf[n], acc[4 + m][n], 0, 0, 0);
      __builtin_amdgcn_s_setprio(0);
      asm volatile("s_waitcnt vmcnt(4)" ::: "memory");   // tile i+1 landed; i+2 in flight
      __builtin_amdgcn_s_barrier();
      __builtin_amdgcn_sched_barrier(0);
    } else {
      // ---------- single phase: all frags; stage whole tile i+2
      #pragma unroll
      for (int n = 0; n < 4; ++n)
        bf[n] = *(const short8*)(rb + BM * 32 + (wn * WCOLS + n * 16 + l15) * 32 + lg * 8);
      #pragma unroll
      for (int m = 0; m < 4; ++m)
        af[m] = *(const short8*)(rb + (wm * WROWS + m * 16 + l15) * 32 + lg * 8);
      if (st) {
        gload_lds16(gA  + kS, wb + wub);
        gload_lds16(gB  + kS, wb + 512 * 8 + wub);
        gload_lds16(gB2 + kS, wb + 1024 * 8 + wub);
      }
      __builtin_amdgcn_s_barrier();
      asm volatile("s_waitcnt lgkmcnt(0)" ::: "memory");
      __builtin_amdgcn_sched_barrier(0);
      __builtin_amdgcn_s_setprio(1);
      #pragma unroll
      for (int m = 0; m < 4; ++m)
        #pragma unroll
        for (int n = 0; n < 4; ++n)
          acc[m][n] = __builtin_amdgcn_mfma_f32_16x16x32_bf16(af[m], bf[n], acc[m][n], 0, 0, 0);
      __builtin_amdgcn_s_setprio(0);
      asm volatile("s_waitcnt vmcnt(3)" ::: "memory");
      __builtin_amdgcn_s_barrier();
      __builtin_amdgcn_sched_barrier(0);
    }
    b0 = (b0 == 2) ? 0 : b0 + 1;
    b2 = (b2 == 2) ? 0 : b2 + 1;
  }

  // ---- epilogue
  #pragma unroll
  for (int n = 0; n < 4; ++n) {
    const int col = n0 + wn * WCOLS + n * 16 + l15;
    const float bv = bias[col];
    #pragma unroll
    for (int m = 0; m < MR; ++m) {
      #pragma unroll
      for (int r = 0; r < 4; ++r) {
        const int row = m0 + wm * WROWS + m * 16 + lg * 4 + r;
        const size_t off = (size_t)row * N + col;
        float v = acc[m][n][r] + bv;
        if (EPI == 1) {
          ((float*)out)[off] = v + resid[off];
        } else if (EPI == 2) {
          float gg = 0.5f * v * (1.0f + erff(v * 0.70710678118654752f));
          ((u16*)out)[off] = f2bf(gg);
        } else {
          ((u16*)out)[off] = f2bf(v);
        }
      }
    }
  }
}

// ---------------------------------------------------------------- V transpose: qkv v-section -> vt[b][h][d][t]
__global__ __launch_bounds__(256) void vtrans_k(
    const u16* __restrict__ qkv, u16* __restrict__ vt)
{
  __shared__ u16 tile[DH_][66];
  const int tid = threadIdx.x;
  const int bid = blockIdx.x;
  const int tt = bid & 31;
  const int bh = bid >> 5;            // b*16+h
  const int b  = bh >> 4, h = bh & 15;
  const int t0 = tt * 64;
  const u16* src = qkv + (size_t)b * T_ * QKVN + 2 * E_ + h * DH_;
  #pragma unroll
  for (int it = 0; it < 8; ++it) {
    int c = it * 256 + tid;           // 64 t x 32 dc
    int t = c >> 5, dc = c & 31;
    u16x4 v = *(const u16x4*)(src + (size_t)(t0 + t) * QKVN + dc * 4);
    #pragma unroll
    for (int j = 0; j < 4; ++j) tile[dc * 4 + j][t] = v[j];
  }
  __syncthreads();
  u16* dst = vt + (size_t)bh * DH_ * T_ + t0;
  #pragma unroll
  for (int it = 0; it < 8; ++it) {
    int c = it * 256 + tid;           // 128 d x 16 tc
    int d = c >> 4, tc = c & 15;
    u16x4 v;
    #pragma unroll
    for (int j = 0; j < 4; ++j) v[j] = tile[d][tc * 4 + j];
    *(u16x4*)(dst + (size_t)d * T_ + tc * 4) = v;
  }
}

// ---------------------------------------------------------------- flash attention (causal)
__global__ __launch_bounds__(256) void attn_k(
    const u16* __restrict__ qkv, const u16* __restrict__ vt, u16* __restrict__ o)
{
  const int tid  = threadIdx.x;
  const int lane = tid & 63;
  const int w    = tid >> 6;
  const int l15  = lane & 15, lg = lane >> 4;
  const int bid  = blockIdx.x;
  const int qt = 15 - (bid & 15);
  const int h  = (bid >> 4) & 15;
  const int b  = bid >> 8;
  const int Q0 = qt * 128;
  const int qw = Q0 + w * 32;         // this wave's 32 q-rows

  __shared__ __align__(16) u16 Ks[64 * 128];   // [s][dh], chunk-swizzled
  __shared__ __align__(16) u16 Vs[128 * 64];   // [dh][s], chunk-swizzled
  __shared__ __align__(16) u16 Ps[4][32][72];  // per-wave P [q][s], padded

  const u16* qb  = qkv + (size_t)b * T_ * QKVN + h * DH_;
  const u16* kb  = qb + E_;
  const u16* vtb = vt + (size_t)(b * H_ + h) * DH_ * T_;

  short8 qf[2][4];
  #pragma unroll
  for (int qi = 0; qi < 2; ++qi)
    #pragma unroll
    for (int kk = 0; kk < 4; ++kk)
      qf[qi][kk] = *(const short8*)(qb + (size_t)(qw + qi * 16 + l15) * QKVN + kk * 32 + lg * 8);

  f32x4 oacc[2][8] = {};
  float m_[2][4], l_[2][4];
  #pragma unroll
  for (int qi = 0; qi < 2; ++qi)
    #pragma unroll
    for (int r = 0; r < 4; ++r) { m_[qi][r] = -1e30f; l_[qi][r] = 0.f; }

  const int xr = l15 & 7;
  const float scl = 0.08838834764831845f;   // 1/sqrt(128)
  const int nt = Q0 / 64 + 2;
  const int qmaxw = qw + 31;
  const int wub = (tid & ~63);

  for (int st = 0; st < nt; ++st) {
    const int s0 = st * 64;
    #pragma unroll
    for (int i = 0; i < 4; ++i) {
      int f = i * 256 + tid;
      int r = f >> 4, p = f & 15, c = p ^ (r & 7);
      gload_lds16(kb + (size_t)(s0 + r) * QKVN + c * 8, Ks + (size_t)(i * 256 + wub) * 8);
    }
    #pragma unroll
    for (int i = 0; i < 4; ++i) {
      int f = i * 256 + tid;
      int d = f >> 3, p = f & 7, c = p ^ (d & 7);
      gload_lds16(vtb + (size_t)d * T_ + s0 + c * 8, Vs + (size_t)(i * 256 + wub) * 8);
    }
    __syncthreads();

    if (s0 <= qmaxw) {
      f32x4 sc[2][4] = {};
      #pragma unroll
      for (int sj = 0; sj < 4; ++sj) {
        const int row = sj * 16 + l15;
        #pragma unroll
        for (int kk = 0; kk < 4; ++kk) {
          short8 kfr = *(const short8*)(Ks + row * 128 + (((kk * 4 + lg) ^ xr) * 8));
          sc[0][sj] = __builtin_amdgcn_mfma_f32_16x16x32_bf16(qf[0][kk], kfr, sc[0][sj], 0, 0, 0);
          sc[1][sj] = __builtin_amdgcn_mfma_f32_16x16x32_bf16(qf[1][kk], kfr, sc[1][sj], 0, 0, 0);
        }
      }
      const bool needmask = (s0 + 63 > qw);
      #pragma unroll
      for (int qi = 0; qi < 2; ++qi)
        #pragma unroll
        for (int sj = 0; sj < 4; ++sj)
          #pragma unroll
          for (int r = 0; r < 4; ++r) {
            float v = sc[qi][sj][r] * scl;
            if (needmask) {
              int s = s0 + sj * 16 + l15;
              int q = qw + qi * 16 + lg * 4 + r;
              if (s > q) v = -1e30f;
            }
            sc[qi][sj][r] = v;
          }
      #pragma unroll
      for (int qi = 0; qi < 2; ++qi) {
        float tmax[4], alpha[4], rsum[4];
        #pragma unroll
        for (int r = 0; r < 4; ++r)
          tmax[r] = fmaxf(fmaxf(sc[qi][0][r], sc[qi][1][r]), fmaxf(sc[qi][2][r], sc[qi][3][r]));
        #pragma unroll
        for (int r = 0; r < 4; ++r)
          #pragma unroll
          for (int m = 1; m < 16; m <<= 1) tmax[r] = fmaxf(tmax[r], __shfl_xor(tmax[r], m));
        #pragma unroll
        for (int r = 0; r < 4; ++r) {
          float mn = fmaxf(m_[qi][r], tmax[r]);
          alpha[r] = __expf(m_[qi][r] - mn);
          m_[qi][r] = mn;
          rsum[r] = 0.f;
        }
        #pragma unroll
        for (int sj = 0; sj < 4; ++sj)
          #pragma unroll
          for (int r = 0; r < 4; ++r) {
            float p = __expf(sc[qi][sj][r] - m_[qi][r]);
            rsum[r] += p;
            Ps[w][qi * 16 + lg * 4 + r][sj * 16 + l15] = f2bf(p);
          }
        #pragma unroll
        for (int r = 0; r < 4; ++r) {
          #pragma unroll
          for (int m = 1; m < 16; m <<= 1) rsum[r] += __shfl_xor(rsum[r], m);
          l_[qi][r] = l_[qi][r] * alpha[r] + rsum[r];
        }
        #pragma unroll
        for (int dj = 0; dj < 8; ++dj)
          #pragma unroll
          for (int r = 0; r < 4; ++r) oacc[qi][dj][r] *= alpha[r];
      }
      asm volatile("s_waitcnt lgkmcnt(0)" ::: "memory");
      __builtin_amdgcn_sched_barrier(0);
      #pragma unroll
      for (int ks = 0; ks < 2; ++ks) {
        short8 pf0 = *(const short8*)(&Ps[w][l15][ks * 32 + lg * 8]);
        short8 pf1 = *(const short8*)(&Ps[w][16 + l15][ks * 32 + lg * 8]);
        #pragma unroll
        for (int dj = 0; dj < 8; ++dj) {
          const int row = dj * 16 + l15;
          short8 vfr = *(const short8*)(Vs + row * 64 + (((ks * 4 + lg) ^ xr) * 8));
          oacc[0][dj] = __builtin_amdgcn_mfma_f32_16x16x32_bf16(pf0, vfr, oacc[0][dj], 0, 0, 0);
          oacc[1][dj] = __builtin_amdgcn_mfma_f32_16x16x32_bf16(pf1, vfr, oacc[1][dj], 0, 0, 0);
        }
      }
    }
    __syncthreads();
  }

  float inv[2][4];
  #pragma unroll
  for (int qi = 0; qi < 2; ++qi)
    #pragma unroll
    for (int r = 0; r < 4; ++r) inv[qi][r] = 1.0f / l_[qi][r];
  u16* ob = o + (size_t)(b * T_ + qw) * E_ + h * DH_;
  #pragma unroll
  for (int qi = 0; qi < 2; ++qi)
    #pragma unroll
    for (int dj = 0; dj < 8; ++dj)
      #pragma unroll
      for (int r = 0; r < 4; ++r)
        ob[(size_t)(qi * 16 + lg * 4 + r) * E_ + dj * 16 + l15] = f2bf(oacc[qi][dj][r] * inv[qi][r]);
}

// ---------------------------------------------------------------- launch
extern "C" void kernel_launch(void* const* d_in, const int* in_sizes, int n_in,
                              void* d_out, int out_size, void* d_ws, size_t ws_size,
                              hipStream_t stream)
{
  const float* x  = (const float*)d_in[0];
  const float* wq = (const float*)d_in[1];
  const float* bq = (const float*)d_in[2];
  const float* wk = (const float*)d_in[3];
  const float* bk = (const float*)d_in[4];
  const float* wv = (const float*)d_in[5];
  const float* bv = (const float*)d_in[6];
  const float* wo = (const float*)d_in[7];
  const float* bo = (const float*)d_in[8];
  const float* w1 = (const float*)d_in[9];
  const float* b1 = (const float*)d_in[10];
  const float* w2 = (const float*)d_in[11];
  const float* b2 = (const float*)d_in[12];
  const float* g1 = (const float*)d_in[13];
  const float* g2 = (const float*)d_in[14];
  float* xout = (float*)d_out;

  if (ws_size < 201351168u) return;   // need ~192 MB scratch

  char* ws = (char*)d_ws;
  u16*   wqkv_t = (u16*)(ws + 0);            // 25,165,824
  u16*   h1     = (u16*)(ws + 25165824);     // 16,777,216
  u16*   qkv    = (u16*)(ws + 41943040);     // 50,331,648
  u16*   vt     = (u16*)(ws + 92274688);     // 16,777,216
  u16*   o_     = (u16*)(ws + 109051904);    // 16,777,216
  u16*   wo_t   = (u16*)(ws + 125829120);    //  8,388,608
  u16*   w1_t   = (u16*)(ws + 134217728);    // 33,554,432
  u16*   w2_t   = (u16*)(ws + 167772160);    // 33,554,432
  float* bqkv   = (float*)(ws + 201326592);  //     24,576
  u16*   u_     = (u16*)(ws + 0);            // 67,108,864 (aliases dead wqkv_t/h1/qkv-prefix)
  u16*   h2     = vt;                        // aliases dead vt
  float* x2     = xout;                      // d_out doubles as residual-2 buffer

  prep_qkv<<<(QKVN * E_) / 256, 256, 0, stream>>>(wq, wk, wv, bq, bk, bv, wqkv_t, bqkv);
  prep_t<<<(E_ * E_) / 256, 256, 0, stream>>>(wo, wo_t, 11, E_);
  prep_t<<<(4 * E_ * E_) / 256, 256, 0, stream>>>(w1, w1_t, 11, 4 * E_);
  prep_t<<<(4 * E_ * E_) / 256, 256, 0, stream>>>(w2, w2_t, 13, E_);

  rmsnorm_k<<<NTOK, 256, 0, stream>>>(x, g1, h1);
  gemm3<256, 256, 0><<<(NTOK / 256) * (QKVN / 256), 512, 0, stream>>>(h1, wqkv_t, bqkv, nullptr, qkv, NTOK, QKVN, E_);
  vtrans_k<<<B_ * H_ * (T_ / 64), 256, 0, stream>>>(qkv, vt);
  attn_k<<<B_ * H_ * (T_ / 16 / 8), 256, 0, stream>>>(qkv, vt, o_);
  gemm3<128, 256, 1><<<(NTOK / 128) * (E_ / 256), 512, 0, stream>>>(o_, wo_t, bo, x, x2, NTOK, E_, E_);
  rmsnorm_k<<<NTOK, 256, 0, stream>>>(x2, g2, h2);
  gemm3<256, 256, 2><<<(NTOK / 256) * (4 * E_ / 256), 512, 0, stream>>>(h2, w1_t, b1, nullptr, u_, NTOK, 4 * E_, E_);
  gemm3<128, 256, 1><<<(NTOK / 128) * (E_ / 256), 512, 0, stream>>>(u_, w2_t, b2, x2, xout, NTOK, E_, 4 * E_);
}